// Round 1
// baseline (652.243 us; speedup 1.0000x reference)
//
#include <hip/hip_runtime.h>
#include <math.h>

namespace {
constexpr int kNS = 16;
constexpr int kNV = 4;
constexpr int kNG = 50;
constexpr int kHID = 64;
constexpr int kAttr = kNS + 3 * kNV;      // 28
constexpr int kWNUM = (kNS + kNV) * kNS + (kNS + kNV) * kNV;  // 400
constexpr float kStep = 5.0f / 49.0f;
constexpr float kCoeff = -0.5f / (kStep * kStep);
constexpr float kSqrt3 = 1.7320508075688772f;
constexpr float kInvSqrt3 = 0.57735026918962576f;
constexpr float kInvSqrt20 = 0.22360679774997896f;
constexpr int kThreads = 256;
constexpr int kLdsStride = 37;  // 36 floats/thread + odd stride -> 2 lanes/bank (free)
}  // namespace

// Per-thread LDS slot layout:
//   [0..15]  = o0[0..15] = node_attr[src, :16]          (also used as ss[] in phase 1)
//   [16..19] = o0[16..19] = (in_1o . sh_1o)/sqrt3
//   [20..35] = node_attr[dst, :16]                      (ds[] in phase 1)

__global__ __launch_bounds__(kThreads) void tfn_edge_kernel(
    const float* __restrict__ node_attr, const float* __restrict__ pos,
    const float* __restrict__ W1, const float* __restrict__ b1,
    const float* __restrict__ W2, const float* __restrict__ b2,
    const int* __restrict__ edge_index, float* __restrict__ agg,
    float* __restrict__ cnt, int E) {
  __shared__ float lds[kThreads * kLdsStride];
  const int e = blockIdx.x * blockDim.x + threadIdx.x;
  if (e >= E) return;
  float* q = lds + threadIdx.x * kLdsStride;

  const int src = edge_index[e];
  const int dst = edge_index[E + e];

  // ---- geometry ----
  const float psx = pos[src * 3 + 0], psy = pos[src * 3 + 1], psz = pos[src * 3 + 2];
  const float pdx = pos[dst * 3 + 0], pdy = pos[dst * 3 + 1], pdz = pos[dst * 3 + 2];
  const float vx = pdx - psx, vy = pdy - psy, vz = pdz - psz;
  const float dist = sqrtf(vx * vx + vy * vy + vz * vz);
  const float rinv = 1.0f / fmaxf(dist, 1e-8f);
  const float sh0 = kSqrt3 * (vy * rinv);  // sh_1o components
  const float sh1 = kSqrt3 * (vz * rinv);
  const float sh2 = kSqrt3 * (vx * rinv);

  // ---- gather node features ----
  const float* nas = node_attr + (size_t)src * kAttr;
  const float* nad = node_attr + (size_t)dst * kAttr;
  const float4 sa = *(const float4*)(nas + 0);
  const float4 sb = *(const float4*)(nas + 4);
  const float4 sc = *(const float4*)(nas + 8);
  const float4 sd = *(const float4*)(nas + 12);
  const float4 va = *(const float4*)(nas + 16);
  const float4 vb = *(const float4*)(nas + 20);
  const float4 vc = *(const float4*)(nas + 24);
  const float4 da = *(const float4*)(nad + 0);
  const float4 db = *(const float4*)(nad + 4);
  const float4 dc = *(const float4*)(nad + 8);
  const float4 dd = *(const float4*)(nad + 12);

  q[0] = sa.x;  q[1] = sa.y;  q[2] = sa.z;  q[3] = sa.w;
  q[4] = sb.x;  q[5] = sb.y;  q[6] = sb.z;  q[7] = sb.w;
  q[8] = sc.x;  q[9] = sc.y;  q[10] = sc.z; q[11] = sc.w;
  q[12] = sd.x; q[13] = sd.y; q[14] = sd.z; q[15] = sd.w;
  q[20] = da.x; q[21] = da.y; q[22] = da.z; q[23] = da.w;
  q[24] = db.x; q[25] = db.y; q[26] = db.z; q[27] = db.w;
  q[28] = dc.x; q[29] = dc.y; q[30] = dc.z; q[31] = dc.w;
  q[32] = dd.x; q[33] = dd.y; q[34] = dd.z; q[35] = dd.w;

  // in_1o rows (kept in registers; only ever statically indexed)
  const float v10 = va.x, v11 = va.y, v12 = va.z;
  const float v13 = va.w, v14 = vb.x, v15 = vb.y;
  const float v16 = vb.z, v17 = vb.w, v18 = vc.x;
  const float v19 = vc.y, v1a = vc.z, v1b = vc.w;

  // o0 tail: (in_1o . sh_1o)/sqrt3
  q[16] = (v10 * sh0 + v11 * sh1 + v12 * sh2) * kInvSqrt3;
  q[17] = (v13 * sh0 + v14 * sh1 + v15 * sh2) * kInvSqrt3;
  q[18] = (v16 * sh0 + v17 * sh1 + v18 * sh2) * kInvSqrt3;
  q[19] = (v19 * sh0 + v1a * sh1 + v1b * sh2) * kInvSqrt3;

  // ---- phase 1: h = relu(ef @ W1 + b1), W1 rows read via uniform (scalar) loads
  float h[kHID];
#pragma unroll
  for (int j = 0; j < kHID; j++) h[j] = b1[j];

#pragma unroll 1
  for (int k = 0; k < kNG; k++) {
    const float d = dist - (float)k * kStep + 1e-6f;
    const float a = __expf(kCoeff * d * d);
    const float* w = W1 + k * kHID;
#pragma unroll
    for (int j = 0; j < kHID; j++) h[j] = fmaf(a, w[j], h[j]);
  }
#pragma unroll 1
  for (int k = 0; k < 2 * kNS; k++) {
    const float a = q[k + ((k >= kNS) ? 4 : 0)];  // ss at [0..15], ds at [20..35]
    const float* w = W1 + (kNG + k) * kHID;
#pragma unroll
    for (int j = 0; j < kHID; j++) h[j] = fmaf(a, w[j], h[j]);
  }
#pragma unroll
  for (int j = 0; j < kHID; j++) h[j] = fmaxf(h[j], 0.0f);

  // ---- phase 2: w = h @ W2 + b2 in 16-column chunks, contracted on the fly
  float msg[kAttr];
#pragma unroll
  for (int j = 0; j < kAttr; j++) msg[j] = 0.0f;

  // 0e block: chunk c covers w columns [c*16, c*16+16) == w_0e row i=c
#pragma unroll 1
  for (int c = 0; c < kNS + kNV; c++) {
    const float* w2 = W2 + c * kNS;
    float wc[16];
#pragma unroll
    for (int j = 0; j < 16; j++) wc[j] = b2[c * kNS + j];
#pragma unroll
    for (int k = 0; k < kHID; k++) {
      const float hv = h[k];
      const float* wr = w2 + k * kWNUM;
#pragma unroll
      for (int j = 0; j < 16; j++) wc[j] = fmaf(hv, wr[j], wc[j]);
    }
    const float s = q[c] * kInvSqrt20;
#pragma unroll
    for (int j = 0; j < 16; j++) msg[j] = fmaf(s, wc[j], msg[j]);
  }

  // 1o block, chunks t=0..3: w columns [320+16t, 336+16t) == i=4t..4t+3 (i<16)
#pragma unroll 1
  for (int t = 0; t < 4; t++) {
    const int cb = (kNS + kNV) * kNS + t * 16;
    const float* w2 = W2 + cb;
    float wc[16];
#pragma unroll
    for (int j = 0; j < 16; j++) wc[j] = b2[cb + j];
#pragma unroll
    for (int k = 0; k < kHID; k++) {
      const float hv = h[k];
      const float* wr = w2 + k * kWNUM;
#pragma unroll
      for (int j = 0; j < 16; j++) wc[j] = fmaf(hv, wr[j], wc[j]);
    }
#pragma unroll
    for (int di = 0; di < 4; di++) {
      const float s = q[4 * t + di] * kInvSqrt20;  // o1[i,c] = ss[i]*sh[c], i<16
      const float a0 = s * sh0, a1 = s * sh1, a2 = s * sh2;
#pragma unroll
      for (int o = 0; o < 4; o++) {
        const float wv = wc[di * 4 + o];
        msg[16 + o * 3 + 0] = fmaf(a0, wv, msg[16 + o * 3 + 0]);
        msg[16 + o * 3 + 1] = fmaf(a1, wv, msg[16 + o * 3 + 1]);
        msg[16 + o * 3 + 2] = fmaf(a2, wv, msg[16 + o * 3 + 2]);
      }
    }
  }

  // 1o tail chunk: i=16..19, o1 rows are in_1o (registers, statically indexed)
  {
    const int cb = (kNS + kNV) * kNS + 64;
    const float* w2 = W2 + cb;
    float wc[16];
#pragma unroll
    for (int j = 0; j < 16; j++) wc[j] = b2[cb + j];
#pragma unroll
    for (int k = 0; k < kHID; k++) {
      const float hv = h[k];
      const float* wr = w2 + k * kWNUM;
#pragma unroll
      for (int j = 0; j < 16; j++) wc[j] = fmaf(hv, wr[j], wc[j]);
    }
    const float v1r[4][3] = {{v10, v11, v12}, {v13, v14, v15},
                             {v16, v17, v18}, {v19, v1a, v1b}};
#pragma unroll
    for (int di = 0; di < 4; di++) {
#pragma unroll
      for (int o = 0; o < 4; o++) {
        const float wv = wc[di * 4 + o] * kInvSqrt20;
        msg[16 + o * 3 + 0] = fmaf(v1r[di][0], wv, msg[16 + o * 3 + 0]);
        msg[16 + o * 3 + 1] = fmaf(v1r[di][1], wv, msg[16 + o * 3 + 1]);
        msg[16 + o * 3 + 2] = fmaf(v1r[di][2], wv, msg[16 + o * 3 + 2]);
      }
    }
  }

  // ---- scatter ----
  float* ap = agg + (size_t)dst * kAttr;
#pragma unroll
  for (int j = 0; j < kAttr; j++) atomicAdd(ap + j, msg[j]);
  atomicAdd(cnt + dst, 1.0f);
}

__global__ __launch_bounds__(256) void tfn_finalize_kernel(
    const float* __restrict__ node_attr, const float* __restrict__ cnt,
    float* __restrict__ out, int total) {
  const int i = blockIdx.x * blockDim.x + threadIdx.x;
  if (i >= total) return;
  const int n = i / kAttr;
  const float c = fmaxf(cnt[n], 1.0f);
  out[i] = node_attr[i] + out[i] / c;
}

extern "C" void kernel_launch(void* const* d_in, const int* in_sizes, int n_in,
                              void* d_out, int out_size, void* d_ws, size_t ws_size,
                              hipStream_t stream) {
  const float* node_attr = (const float*)d_in[0];
  const float* pos = (const float*)d_in[1];
  const float* W1 = (const float*)d_in[2];
  const float* b1 = (const float*)d_in[3];
  const float* W2 = (const float*)d_in[4];
  const float* b2 = (const float*)d_in[5];
  const int* edge_index = (const int*)d_in[6];

  const int N = in_sizes[0] / kAttr;
  const int E = in_sizes[6] / 2;

  float* agg = (float*)d_out;   // accumulate messages directly into d_out
  float* cnt = (float*)d_ws;    // N floats of scratch

  hipMemsetAsync(d_out, 0, (size_t)out_size * sizeof(float), stream);
  hipMemsetAsync(d_ws, 0, (size_t)N * sizeof(float), stream);

  const int blocks = (E + kThreads - 1) / kThreads;
  tfn_edge_kernel<<<blocks, kThreads, 0, stream>>>(
      node_attr, pos, W1, b1, W2, b2, edge_index, agg, cnt, E);

  const int total = N * kAttr;
  tfn_finalize_kernel<<<(total + 255) / 256, 256, 0, stream>>>(
      node_attr, cnt, (float*)d_out, total);
}

// Round 2
// 339.402 us; speedup vs baseline: 1.9217x; 1.9217x over previous
//
#include <hip/hip_runtime.h>
#include <math.h>

namespace {
constexpr int kNS = 16;
constexpr int kNV = 4;
constexpr int kNG = 50;
constexpr int kHID = 64;
constexpr int kAttr = kNS + 3 * kNV;      // 28
constexpr int kWNUM = (kNS + kNV) * kNS + (kNS + kNV) * kNV;  // 400
constexpr float kStep = 5.0f / 49.0f;
constexpr float kCoeff = -0.5f / (kStep * kStep);
constexpr float kSqrt3 = 1.7320508075688772f;
constexpr float kInvSqrt3 = 0.57735026918962576f;
constexpr float kInvSqrt20 = 0.22360679774997896f;
constexpr int kThreads = 256;
constexpr int kLdsStride = 37;  // 36 floats/thread + odd stride -> 2 lanes/bank (free)
}  // namespace

// Per-thread LDS slot layout (q):
//   [0..15]  = o0[0..15] = node_attr[src, :16]   (runtime-indexed in phase 1/2)
//   [16..19] = o0[16..19] = (in_1o . sh_1o)/sqrt3
//   [20..35] = node_attr[dst, :16]

__device__ __forceinline__ void edge_compute(
    int src, int dst, const float* __restrict__ node_attr,
    const float* __restrict__ pos, const float* __restrict__ W1,
    const float* __restrict__ b1, const float* __restrict__ W2,
    const float* __restrict__ b2, float* q, float msg[kAttr]) {
  // ---- geometry ----
  const float psx = pos[src * 3 + 0], psy = pos[src * 3 + 1], psz = pos[src * 3 + 2];
  const float pdx = pos[dst * 3 + 0], pdy = pos[dst * 3 + 1], pdz = pos[dst * 3 + 2];
  const float vx = pdx - psx, vy = pdy - psy, vz = pdz - psz;
  const float dist = sqrtf(vx * vx + vy * vy + vz * vz);
  const float rinv = 1.0f / fmaxf(dist, 1e-8f);
  const float sh0 = kSqrt3 * (vy * rinv);
  const float sh1 = kSqrt3 * (vz * rinv);
  const float sh2 = kSqrt3 * (vx * rinv);

  // ---- gather node features ----
  const float* nas = node_attr + (size_t)src * kAttr;
  const float* nad = node_attr + (size_t)dst * kAttr;
  const float4 sa = *(const float4*)(nas + 0);
  const float4 sb = *(const float4*)(nas + 4);
  const float4 sc = *(const float4*)(nas + 8);
  const float4 sd = *(const float4*)(nas + 12);
  const float4 va = *(const float4*)(nas + 16);
  const float4 vb = *(const float4*)(nas + 20);
  const float4 vc = *(const float4*)(nas + 24);
  const float4 da = *(const float4*)(nad + 0);
  const float4 db = *(const float4*)(nad + 4);
  const float4 dc = *(const float4*)(nad + 8);
  const float4 dd = *(const float4*)(nad + 12);

  q[0] = sa.x;  q[1] = sa.y;  q[2] = sa.z;  q[3] = sa.w;
  q[4] = sb.x;  q[5] = sb.y;  q[6] = sb.z;  q[7] = sb.w;
  q[8] = sc.x;  q[9] = sc.y;  q[10] = sc.z; q[11] = sc.w;
  q[12] = sd.x; q[13] = sd.y; q[14] = sd.z; q[15] = sd.w;
  q[20] = da.x; q[21] = da.y; q[22] = da.z; q[23] = da.w;
  q[24] = db.x; q[25] = db.y; q[26] = db.z; q[27] = db.w;
  q[28] = dc.x; q[29] = dc.y; q[30] = dc.z; q[31] = dc.w;
  q[32] = dd.x; q[33] = dd.y; q[34] = dd.z; q[35] = dd.w;

  const float v10 = va.x, v11 = va.y, v12 = va.z;
  const float v13 = va.w, v14 = vb.x, v15 = vb.y;
  const float v16 = vb.z, v17 = vb.w, v18 = vc.x;
  const float v19 = vc.y, v1a = vc.z, v1b = vc.w;

  q[16] = (v10 * sh0 + v11 * sh1 + v12 * sh2) * kInvSqrt3;
  q[17] = (v13 * sh0 + v14 * sh1 + v15 * sh2) * kInvSqrt3;
  q[18] = (v16 * sh0 + v17 * sh1 + v18 * sh2) * kInvSqrt3;
  q[19] = (v19 * sh0 + v1a * sh1 + v1b * sh2) * kInvSqrt3;

  // ---- phase 1: h = relu(ef @ W1 + b1) (W1 via wave-uniform scalar loads)
  float h[kHID];
#pragma unroll
  for (int j = 0; j < kHID; j++) h[j] = b1[j];

#pragma unroll 1
  for (int k = 0; k < kNG; k++) {
    const float d = dist - (float)k * kStep + 1e-6f;
    const float a = __expf(kCoeff * d * d);
    const float* w = W1 + k * kHID;
#pragma unroll
    for (int j = 0; j < kHID; j++) h[j] = fmaf(a, w[j], h[j]);
  }
#pragma unroll 1
  for (int k = 0; k < 2 * kNS; k++) {
    const float a = q[k + ((k >= kNS) ? 4 : 0)];
    const float* w = W1 + (kNG + k) * kHID;
#pragma unroll
    for (int j = 0; j < kHID; j++) h[j] = fmaf(a, w[j], h[j]);
  }
#pragma unroll
  for (int j = 0; j < kHID; j++) h[j] = fmaxf(h[j], 0.0f);

  // ---- phase 2: w = h @ W2 + b2 in 16-col chunks, contracted on the fly
  // 0e block
#pragma unroll 1
  for (int c = 0; c < kNS + kNV; c++) {
    const float* w2 = W2 + c * kNS;
    float wc[16];
#pragma unroll
    for (int j = 0; j < 16; j++) wc[j] = b2[c * kNS + j];
#pragma unroll
    for (int k = 0; k < kHID; k++) {
      const float hv = h[k];
      const float* wr = w2 + k * kWNUM;
#pragma unroll
      for (int j = 0; j < 16; j++) wc[j] = fmaf(hv, wr[j], wc[j]);
    }
    const float s = q[c] * kInvSqrt20;
#pragma unroll
    for (int j = 0; j < 16; j++) msg[j] = fmaf(s, wc[j], msg[j]);
  }

  // 1o block, i = 0..15 (o1 rows = ss[i]*sh)
#pragma unroll 1
  for (int t = 0; t < 4; t++) {
    const int cb = (kNS + kNV) * kNS + t * 16;
    const float* w2 = W2 + cb;
    float wc[16];
#pragma unroll
    for (int j = 0; j < 16; j++) wc[j] = b2[cb + j];
#pragma unroll
    for (int k = 0; k < kHID; k++) {
      const float hv = h[k];
      const float* wr = w2 + k * kWNUM;
#pragma unroll
      for (int j = 0; j < 16; j++) wc[j] = fmaf(hv, wr[j], wc[j]);
    }
#pragma unroll
    for (int di = 0; di < 4; di++) {
      const float s = q[4 * t + di] * kInvSqrt20;
      const float a0 = s * sh0, a1 = s * sh1, a2 = s * sh2;
#pragma unroll
      for (int o = 0; o < 4; o++) {
        const float wv = wc[di * 4 + o];
        msg[16 + o * 3 + 0] = fmaf(a0, wv, msg[16 + o * 3 + 0]);
        msg[16 + o * 3 + 1] = fmaf(a1, wv, msg[16 + o * 3 + 1]);
        msg[16 + o * 3 + 2] = fmaf(a2, wv, msg[16 + o * 3 + 2]);
      }
    }
  }

  // 1o tail, i = 16..19 (o1 rows = in_1o)
  {
    const int cb = (kNS + kNV) * kNS + 64;
    const float* w2 = W2 + cb;
    float wc[16];
#pragma unroll
    for (int j = 0; j < 16; j++) wc[j] = b2[cb + j];
#pragma unroll
    for (int k = 0; k < kHID; k++) {
      const float hv = h[k];
      const float* wr = w2 + k * kWNUM;
#pragma unroll
      for (int j = 0; j < 16; j++) wc[j] = fmaf(hv, wr[j], wc[j]);
    }
    const float v1r[4][3] = {{v10, v11, v12}, {v13, v14, v15},
                             {v16, v17, v18}, {v19, v1a, v1b}};
#pragma unroll
    for (int di = 0; di < 4; di++) {
#pragma unroll
      for (int o = 0; o < 4; o++) {
        const float wv = wc[di * 4 + o] * kInvSqrt20;
        msg[16 + o * 3 + 0] = fmaf(v1r[di][0], wv, msg[16 + o * 3 + 0]);
        msg[16 + o * 3 + 1] = fmaf(v1r[di][1], wv, msg[16 + o * 3 + 1]);
        msg[16 + o * 3 + 2] = fmaf(v1r[di][2], wv, msg[16 + o * 3 + 2]);
      }
    }
  }
}

// ---------- sort-by-dst machinery ----------
__global__ __launch_bounds__(256) void hist_kernel(
    const int* __restrict__ edge_index, int* __restrict__ cnt, int E) {
  const int e = blockIdx.x * blockDim.x + threadIdx.x;
  if (e >= E) return;
  atomicAdd(cnt + edge_index[E + e], 1);
}

__global__ __launch_bounds__(256) void scan_kernel(
    const int* __restrict__ cnt, int* __restrict__ cur, int N) {
  __shared__ int sums[256];
  const int tid = threadIdx.x;
  const int chunk = (N + 255) / 256;
  const int base = tid * chunk;
  int s = 0;
  for (int j = 0; j < chunk; j++) {
    const int i = base + j;
    if (i < N) s += cnt[i];
  }
  sums[tid] = s;
  __syncthreads();
  for (int d = 1; d < 256; d <<= 1) {
    const int y = (tid >= d) ? sums[tid - d] : 0;
    __syncthreads();
    sums[tid] += y;
    __syncthreads();
  }
  int run = sums[tid] - s;  // exclusive prefix of this thread's chunk
  for (int j = 0; j < chunk; j++) {
    const int i = base + j;
    if (i < N) { cur[i] = run; run += cnt[i]; }
  }
}

__global__ __launch_bounds__(256) void scatter_kernel(
    const int* __restrict__ edge_index, int* __restrict__ cur,
    int* __restrict__ ssrc, int* __restrict__ sdst, int E) {
  const int e = blockIdx.x * blockDim.x + threadIdx.x;
  if (e >= E) return;
  const int s = edge_index[e];
  const int d = edge_index[E + e];
  const int p = atomicAdd(cur + d, 1);
  ssrc[p] = s;
  sdst[p] = d;
}

// ---------- edge kernels ----------
__global__ __launch_bounds__(kThreads) void tfn_edge_sorted_kernel(
    const float* __restrict__ node_attr, const float* __restrict__ pos,
    const float* __restrict__ W1, const float* __restrict__ b1,
    const float* __restrict__ W2, const float* __restrict__ b2,
    const int* __restrict__ ssrc, const int* __restrict__ sdst,
    float* __restrict__ agg, int E) {
  __shared__ float lds[kThreads * kLdsStride];
  const int t = blockIdx.x * blockDim.x + threadIdx.x;
  float* q = lds + threadIdx.x * kLdsStride;

  int srcv = 0, dstv = -1;
  const bool valid = (t < E);
  if (valid) { srcv = ssrc[t]; dstv = sdst[t]; }

  float msg[kAttr];
#pragma unroll
  for (int j = 0; j < kAttr; j++) msg[j] = 0.0f;
  if (valid)
    edge_compute(srcv, dstv, node_attr, pos, W1, b1, W2, b2, q, msg);

  // segmented wave reduction: dst-sorted => runs are contiguous, so
  // dst[i+d]==dst[i] implies everything between is the same segment.
  const int lane = threadIdx.x & 63;
#pragma unroll
  for (int d = 1; d < 64; d <<= 1) {
    const int od = __shfl_down(dstv, d);
    const bool same = (lane + d < 64) && (od == dstv);
#pragma unroll
    for (int j = 0; j < kAttr; j++) {
      const float ov = __shfl_down(msg[j], d);
      if (same) msg[j] += ov;
    }
  }
  const int pd = __shfl_up(dstv, 1);
  if ((lane == 0 || pd != dstv) && dstv >= 0) {
    float* ap = agg + (size_t)dstv * kAttr;
#pragma unroll
    for (int j = 0; j < kAttr; j++) atomicAdd(ap + j, msg[j]);
  }
}

// fallback (small ws): one atomic per message element
__global__ __launch_bounds__(kThreads) void tfn_edge_legacy_kernel(
    const float* __restrict__ node_attr, const float* __restrict__ pos,
    const float* __restrict__ W1, const float* __restrict__ b1,
    const float* __restrict__ W2, const float* __restrict__ b2,
    const int* __restrict__ edge_index, float* __restrict__ agg, int E) {
  __shared__ float lds[kThreads * kLdsStride];
  const int e = blockIdx.x * blockDim.x + threadIdx.x;
  if (e >= E) return;
  float* q = lds + threadIdx.x * kLdsStride;
  const int src = edge_index[e];
  const int dst = edge_index[E + e];
  float msg[kAttr];
#pragma unroll
  for (int j = 0; j < kAttr; j++) msg[j] = 0.0f;
  edge_compute(src, dst, node_attr, pos, W1, b1, W2, b2, q, msg);
  float* ap = agg + (size_t)dst * kAttr;
#pragma unroll
  for (int j = 0; j < kAttr; j++) atomicAdd(ap + j, msg[j]);
}

__global__ __launch_bounds__(256) void tfn_finalize_kernel(
    const float* __restrict__ node_attr, const int* __restrict__ cnt,
    float* __restrict__ out, int total) {
  const int i = blockIdx.x * blockDim.x + threadIdx.x;
  if (i >= total) return;
  const int n = i / kAttr;
  const float c = fmaxf((float)cnt[n], 1.0f);
  out[i] = node_attr[i] + out[i] / c;
}

extern "C" void kernel_launch(void* const* d_in, const int* in_sizes, int n_in,
                              void* d_out, int out_size, void* d_ws, size_t ws_size,
                              hipStream_t stream) {
  const float* node_attr = (const float*)d_in[0];
  const float* pos = (const float*)d_in[1];
  const float* W1 = (const float*)d_in[2];
  const float* b1 = (const float*)d_in[3];
  const float* W2 = (const float*)d_in[4];
  const float* b2 = (const float*)d_in[5];
  const int* edge_index = (const int*)d_in[6];

  const int N = in_sizes[0] / kAttr;
  const int E = in_sizes[6] / 2;

  float* agg = (float*)d_out;
  int* cnt = (int*)d_ws;

  hipMemsetAsync(d_out, 0, (size_t)out_size * sizeof(float), stream);
  hipMemsetAsync(cnt, 0, (size_t)N * sizeof(int), stream);

  const int eblocks = (E + 255) / 256;
  hist_kernel<<<eblocks, 256, 0, stream>>>(edge_index, cnt, E);

  const size_t need = (size_t)(2 * N + 2 * E) * sizeof(int);
  if (ws_size >= need) {
    int* cur = cnt + N;
    int* ssrc = cur + N;
    int* sdst = ssrc + E;
    scan_kernel<<<1, 256, 0, stream>>>(cnt, cur, N);
    scatter_kernel<<<eblocks, 256, 0, stream>>>(edge_index, cur, ssrc, sdst, E);
    tfn_edge_sorted_kernel<<<(E + kThreads - 1) / kThreads, kThreads, 0, stream>>>(
        node_attr, pos, W1, b1, W2, b2, ssrc, sdst, agg, E);
  } else {
    tfn_edge_legacy_kernel<<<(E + kThreads - 1) / kThreads, kThreads, 0, stream>>>(
        node_attr, pos, W1, b1, W2, b2, edge_index, agg, E);
  }

  const int total = N * kAttr;
  tfn_finalize_kernel<<<(total + 255) / 256, 256, 0, stream>>>(
      node_attr, cnt, (float*)d_out, total);
}

// Round 4
// 144.606 us; speedup vs baseline: 4.5105x; 2.3471x over previous
//
#include <hip/hip_runtime.h>
#include <math.h>

typedef short short8 __attribute__((ext_vector_type(8)));
typedef float f32x4 __attribute__((ext_vector_type(4)));
typedef unsigned int u32x4 __attribute__((ext_vector_type(4)));
typedef unsigned int u32x2 __attribute__((ext_vector_type(2)));

namespace {
constexpr int kNS = 16;
constexpr int kNV = 4;
constexpr int kNG = 50;
constexpr int kHID = 64;
constexpr int kAttr = 28;                 // NS + 3*NV
constexpr int kWNUM = 400;
constexpr float kStep = 5.0f / 49.0f;
constexpr float kCoeff = -0.5f / (kStep * kStep);
constexpr float kSqrt3 = 1.7320508075688772f;
constexpr float kInvSqrt3 = 0.57735026918962576f;
constexpr float kInvSqrt20 = 0.22360679774997896f;
// Row = 208 B (13 granules). 208B stride = 52 words == 20 mod 32 -> 16 rows
// spread over 8 bank-offset classes (2 lanes/bank = free, m136). No XOR
// swizzle: round-3's XOR escaped the 192B row (non-power-of-2) and corrupted
// neighbor rows / ax[] -> NaN.
constexpr int kRowB = 208;
constexpr int kAuxB = 48;                 // aux row: 20 bf16 o0 (+pad)
constexpr int kImg1Bytes = 96 * 64 * 2;   // 12288
constexpr int kImg2Bytes = 64 * 400 * 2;  // 51200
}  // namespace

__device__ __forceinline__ unsigned short f2bf(float x) {
  unsigned u = __float_as_uint(x);
  return (unsigned short)((u + 0x7FFFu + ((u >> 16) & 1u)) >> 16);
}
__device__ __forceinline__ unsigned pack2(float lo, float hi) {
  return (unsigned)f2bf(lo) | ((unsigned)f2bf(hi) << 16);
}
__device__ __forceinline__ float bf2f(unsigned short v) {
  return __uint_as_float(((unsigned)v) << 16);
}

// ---------- prep: pack W1 (padded 82->96, fragment-ordered) and W2 into bf16 images
// img layout: element (k, n) at byte ((k>>3)*W + n)*16 + 2*(k&7) => one lane's
// 8 contiguous k at fixed n is one aligned 16B chunk; lanes n-contiguous coalesce.
__global__ __launch_bounds__(256) void prep_kernel(
    const float* __restrict__ W1, const float* __restrict__ W2,
    unsigned short* __restrict__ img1, unsigned short* __restrict__ img2) {
  const int i = blockIdx.x * 256 + threadIdx.x;
  if (i < 96 * 64) {
    const int m = i >> 6, n = i & 63;
    float v = 0.0f;
    if (m < 50) v = W1[m * 64 + n];                        // gaussian rows 0..49
    else if (m >= 56 && m < 88) v = W1[(m - 6) * 64 + n];  // ss rows 50..65, ds 66..81
    img1[((m >> 3) * 64 + n) * 8 + (m & 7)] = f2bf(v);
  } else if (i < 96 * 64 + 64 * 400) {
    const int j = i - 96 * 64;
    const int m = j / 400, n = j % 400;
    img2[((m >> 3) * 400 + n) * 8 + (m & 7)] = f2bf(W2[m * 400 + n]);
  }
}

// ---------- sort-by-dst machinery ----------
__global__ __launch_bounds__(256) void hist_kernel(
    const int* __restrict__ edge_index, int* __restrict__ cnt, int E) {
  const int e = blockIdx.x * blockDim.x + threadIdx.x;
  if (e >= E) return;
  atomicAdd(cnt + edge_index[E + e], 1);
}

__global__ __launch_bounds__(256) void scan_kernel(
    const int* __restrict__ cnt, int* __restrict__ cur, int N) {
  __shared__ int sums[256];
  const int tid = threadIdx.x;
  const int chunk = (N + 255) / 256;
  const int base = tid * chunk;
  int s = 0;
  for (int j = 0; j < chunk; j++) {
    const int i = base + j;
    if (i < N) s += cnt[i];
  }
  sums[tid] = s;
  __syncthreads();
  for (int d = 1; d < 256; d <<= 1) {
    const int y = (tid >= d) ? sums[tid - d] : 0;
    __syncthreads();
    sums[tid] += y;
    __syncthreads();
  }
  int run = sums[tid] - s;
  for (int j = 0; j < chunk; j++) {
    const int i = base + j;
    if (i < N) { cur[i] = run; run += cnt[i]; }
  }
}

__global__ __launch_bounds__(256) void scatter_kernel(
    const int* __restrict__ edge_index, int* __restrict__ cur,
    int* __restrict__ ssrc, int* __restrict__ sdst, int E) {
  const int e = blockIdx.x * blockDim.x + threadIdx.x;
  if (e >= E) return;
  const int s = edge_index[e];
  const int d = edge_index[E + e];
  const int p = atomicAdd(cur + d, 1);
  ssrc[p] = s;
  sdst[p] = d;
}

// ---------- main MFMA edge kernel ----------
// Per wave: 64 edges (4 groups of 16). All LDS traffic is wave-local (no barriers).
// ub row (208B): chunks 0..11 = ef(96 bf16); then chunks 0..7 overwritten by
// h(64 bf16), chunks 8..11 by sh/v1 f32 stash (after eff hoist); finally
// chunks 0..6 overwritten by msg(28 f32).
__global__ __launch_bounds__(256, 2) void tfn_mfma_kernel(
    const float* __restrict__ node_attr, const float* __restrict__ pos,
    const float* __restrict__ b1, const float* __restrict__ b2,
    const char* __restrict__ img1, const char* __restrict__ img2,
    const int* __restrict__ ssrc, const int* __restrict__ sdst,
    float* __restrict__ agg, int E) {
  __shared__ __align__(16) char ub[256 * kRowB];   // 53248 B
  __shared__ __align__(16) char ax[256 * kAuxB];   // 12288 B

  const int tid = threadIdx.x;
  const int t = blockIdx.x * 256 + tid;
  const int lane = tid & 63;
  const int wv = tid >> 6;
  const int lc = lane & 15, lq = lane >> 4;

  const bool valid = (t < E);
  int src = 0, dstv = -1;
  if (valid) { src = ssrc[t]; dstv = sdst[t]; }
  const int dn = valid ? dstv : 0;

  // ---- geometry ----
  const float psx = pos[src * 3 + 0], psy = pos[src * 3 + 1], psz = pos[src * 3 + 2];
  const float pdx = pos[dn * 3 + 0], pdy = pos[dn * 3 + 1], pdz = pos[dn * 3 + 2];
  const float vx = pdx - psx, vy = pdy - psy, vz = pdz - psz;
  const float dist = sqrtf(vx * vx + vy * vy + vz * vz);
  const float rinv = 1.0f / fmaxf(dist, 1e-8f);
  const float sh0 = kSqrt3 * (vy * rinv);
  const float sh1 = kSqrt3 * (vz * rinv);
  const float sh2 = kSqrt3 * (vx * rinv);

  const float* nas = node_attr + (size_t)src * kAttr;
  const float* nad = node_attr + (size_t)dn * kAttr;
  const float4 sa = *(const float4*)(nas + 0);
  const float4 sb = *(const float4*)(nas + 4);
  const float4 sc4 = *(const float4*)(nas + 8);
  const float4 sd4 = *(const float4*)(nas + 12);
  const float4 va = *(const float4*)(nas + 16);
  const float4 vb = *(const float4*)(nas + 20);
  const float4 vc = *(const float4*)(nas + 24);
  const float4 da = *(const float4*)(nad + 0);
  const float4 db = *(const float4*)(nad + 4);
  const float4 dc4 = *(const float4*)(nad + 8);
  const float4 dd4 = *(const float4*)(nad + 12);

  char* myrow = ub + tid * kRowB;

  // ---- write ef row (96 bf16): [gauss50 | 0x6 | ss16 | ds16 | 0x8] ----
  {
    const float base = dist + 1e-6f;
#pragma unroll
    for (int c = 0; c < 6; ++c) {
      unsigned p[4];
#pragma unroll
      for (int u = 0; u < 4; ++u) {
        const int k = c * 8 + u * 2;
        const float d0 = base - (float)k * kStep;
        const float d1 = base - (float)(k + 1) * kStep;
        p[u] = pack2(__expf(kCoeff * d0 * d0), __expf(kCoeff * d1 * d1));
      }
      *(u32x4*)(myrow + c * 16) = u32x4{p[0], p[1], p[2], p[3]};
    }
    const float d0 = base - 48.0f * kStep, d1 = base - 49.0f * kStep;
    *(u32x4*)(myrow + 6 * 16) =
        u32x4{pack2(__expf(kCoeff * d0 * d0), __expf(kCoeff * d1 * d1)), 0u, 0u, 0u};
    *(u32x4*)(myrow + 7 * 16) =
        u32x4{pack2(sa.x, sa.y), pack2(sa.z, sa.w), pack2(sb.x, sb.y), pack2(sb.z, sb.w)};
    *(u32x4*)(myrow + 8 * 16) =
        u32x4{pack2(sc4.x, sc4.y), pack2(sc4.z, sc4.w), pack2(sd4.x, sd4.y), pack2(sd4.z, sd4.w)};
    *(u32x4*)(myrow + 9 * 16) =
        u32x4{pack2(da.x, da.y), pack2(da.z, da.w), pack2(db.x, db.y), pack2(db.z, db.w)};
    *(u32x4*)(myrow + 10 * 16) =
        u32x4{pack2(dc4.x, dc4.y), pack2(dc4.z, dc4.w), pack2(dd4.x, dd4.y), pack2(dd4.z, dd4.w)};
    *(u32x4*)(myrow + 11 * 16) = u32x4{0u, 0u, 0u, 0u};
  }

  // ---- aux row: o0[20] as bf16 ----
  const float v1f[12] = {va.x, va.y, va.z, va.w, vb.x, vb.y, vb.z, vb.w,
                         vc.x, vc.y, vc.z, vc.w};
  {
    const float t0 = (v1f[0] * sh0 + v1f[1] * sh1 + v1f[2] * sh2) * kInvSqrt3;
    const float t1 = (v1f[3] * sh0 + v1f[4] * sh1 + v1f[5] * sh2) * kInvSqrt3;
    const float t2 = (v1f[6] * sh0 + v1f[7] * sh1 + v1f[8] * sh2) * kInvSqrt3;
    const float t3 = (v1f[9] * sh0 + v1f[10] * sh1 + v1f[11] * sh2) * kInvSqrt3;
    char* myax = ax + tid * kAuxB;
    *(u32x4*)(myax + 0) = u32x4{pack2(sa.x, sa.y), pack2(sa.z, sa.w),
                                pack2(sb.x, sb.y), pack2(sb.z, sb.w)};
    *(u32x4*)(myax + 16) = u32x4{pack2(sc4.x, sc4.y), pack2(sc4.z, sc4.w),
                                 pack2(sd4.x, sd4.y), pack2(sd4.z, sd4.w)};
    *(u32x2*)(myax + 32) = u32x2{pack2(t0, t1), pack2(t2, t3)};
  }

  // ---- hoist ef fragments (B-operand: lane holds ef[e=g*16+lc][k=(ks*4+lq)*8+j]) ----
  short8 eff[4][3];
#pragma unroll
  for (int g = 0; g < 4; ++g) {
    const char* rp = ub + (wv * 64 + g * 16 + lc) * kRowB;
#pragma unroll
    for (int ks = 0; ks < 3; ++ks)
      eff[g][ks] = *(const short8*)(rp + (ks * 4 + lq) * 16);
  }

  // ---- stash sh/v1 as f32 into chunks 8..11 (ef chunks 8..11 now dead) ----
  *(f32x4*)(myrow + 8 * 16) = f32x4{sh0, sh1, sh2, v1f[0]};
  *(f32x4*)(myrow + 9 * 16) = f32x4{v1f[1], v1f[2], v1f[3], v1f[4]};
  *(f32x4*)(myrow + 10 * 16) = f32x4{v1f[5], v1f[6], v1f[7], v1f[8]};
  *(f32x4*)(myrow + 11 * 16) = f32x4{v1f[9], v1f[10], v1f[11], 0.0f};

  // ---- MFMA-1: h[n][e] = relu(b1[n] + sum_k W1p[k][n] ef[e][k]) ----
#pragma unroll
  for (int nt = 0; nt < 4; ++nt) {
    const short8 a0 = *(const short8*)(img1 + ((0 + lq) * 64 + nt * 16 + lc) * 16);
    const short8 a1 = *(const short8*)(img1 + ((4 + lq) * 64 + nt * 16 + lc) * 16);
    const short8 a2 = *(const short8*)(img1 + ((8 + lq) * 64 + nt * 16 + lc) * 16);
    const f32x4 bias = *(const f32x4*)(b1 + nt * 16 + lq * 4);
#pragma unroll
    for (int g = 0; g < 4; ++g) {
      f32x4 acc = bias;
      acc = __builtin_amdgcn_mfma_f32_16x16x32_bf16(a0, eff[g][0], acc, 0, 0, 0);
      acc = __builtin_amdgcn_mfma_f32_16x16x32_bf16(a1, eff[g][1], acc, 0, 0, 0);
      acc = __builtin_amdgcn_mfma_f32_16x16x32_bf16(a2, eff[g][2], acc, 0, 0, 0);
      const unsigned p0 = pack2(fmaxf(acc[0], 0.0f), fmaxf(acc[1], 0.0f));
      const unsigned p1 = pack2(fmaxf(acc[2], 0.0f), fmaxf(acc[3], 0.0f));
      const int row = wv * 64 + g * 16 + lc;
      // n = nt*16 + lq*4 + r -> byte 2n = nt*32 + lq*8
      *(u32x2*)(ub + row * kRowB + nt * 32 + lq * 8) = u32x2{p0, p1};
    }
  }

  // ---- load h fragments (B-operand: lane holds h[k][e=g*16+lc]) ----
  short8 hf[4][2];
#pragma unroll
  for (int g = 0; g < 4; ++g) {
    const char* rp = ub + (wv * 64 + g * 16 + lc) * kRowB;
    hf[g][0] = *(const short8*)(rp + (0 + lq) * 16);
    hf[g][1] = *(const short8*)(rp + (4 + lq) * 16);
  }

  // ---- hoist per-edge sh / v1 (lane owns edge lc of each group) ----
  float shv[4][3], v1h[4][3];
#pragma unroll
  for (int g = 0; g < 4; ++g) {
    const char* rp = ub + (wv * 64 + g * 16 + lc) * kRowB;
#pragma unroll
    for (int c = 0; c < 3; ++c) {
      shv[g][c] = *(const float*)(rp + 128 + 4 * c);
      v1h[g][c] = *(const float*)(rp + 140 + 12 * lq + 4 * c);
    }
  }

  // ---- MFMA-2 + fused contraction. D[n][e]: lane owns edge lc, n = 16nt+4lq+r ----
  float macc0[4][4] = {};
  float macc1[4][4][3] = {};

#pragma unroll 5
  for (int nt = 0; nt < 20; ++nt) {
    const short8 w0 = *(const short8*)(img2 + ((0 + lq) * 400 + nt * 16 + lc) * 16);
    const short8 w1 = *(const short8*)(img2 + ((4 + lq) * 400 + nt * 16 + lc) * 16);
    const f32x4 bias = *(const f32x4*)(b2 + nt * 16 + lq * 4);
#pragma unroll
    for (int g = 0; g < 4; ++g) {
      f32x4 acc = bias;
      acc = __builtin_amdgcn_mfma_f32_16x16x32_bf16(w0, hf[g][0], acc, 0, 0, 0);
      acc = __builtin_amdgcn_mfma_f32_16x16x32_bf16(w1, hf[g][1], acc, 0, 0, 0);
      const int row = wv * 64 + g * 16 + lc;
      const float o0v = bf2f(*(const unsigned short*)(ax + row * kAuxB + 2 * nt));
#pragma unroll
      for (int r = 0; r < 4; ++r) macc0[g][r] = fmaf(o0v, acc[r], macc0[g][r]);
    }
  }
#pragma unroll
  for (int nt = 20; nt < 24; ++nt) {
    const short8 w0 = *(const short8*)(img2 + ((0 + lq) * 400 + nt * 16 + lc) * 16);
    const short8 w1 = *(const short8*)(img2 + ((4 + lq) * 400 + nt * 16 + lc) * 16);
    const f32x4 bias = *(const f32x4*)(b2 + nt * 16 + lq * 4);
#pragma unroll
    for (int g = 0; g < 4; ++g) {
      f32x4 acc = bias;
      acc = __builtin_amdgcn_mfma_f32_16x16x32_bf16(w0, hf[g][0], acc, 0, 0, 0);
      acc = __builtin_amdgcn_mfma_f32_16x16x32_bf16(w1, hf[g][1], acc, 0, 0, 0);
      const int row = wv * 64 + g * 16 + lc;
      // i = 4*(nt-20) + lq, o = r; o1[i] = ss[i] * sh
      const float ssv =
          bf2f(*(const unsigned short*)(ax + row * kAuxB + 2 * (4 * (nt - 20) + lq)));
      float pc[3];
#pragma unroll
      for (int c = 0; c < 3; ++c) pc[c] = ssv * shv[g][c];
#pragma unroll
      for (int r = 0; r < 4; ++r)
#pragma unroll
        for (int c = 0; c < 3; ++c)
          macc1[g][r][c] = fmaf(pc[c], acc[r], macc1[g][r][c]);
    }
  }
  {  // nt = 24: i = 16 + lq, o1 row = in_1o
    const int nt = 24;
    const short8 w0 = *(const short8*)(img2 + ((0 + lq) * 400 + nt * 16 + lc) * 16);
    const short8 w1 = *(const short8*)(img2 + ((4 + lq) * 400 + nt * 16 + lc) * 16);
    const f32x4 bias = *(const f32x4*)(b2 + nt * 16 + lq * 4);
#pragma unroll
    for (int g = 0; g < 4; ++g) {
      f32x4 acc = bias;
      acc = __builtin_amdgcn_mfma_f32_16x16x32_bf16(w0, hf[g][0], acc, 0, 0, 0);
      acc = __builtin_amdgcn_mfma_f32_16x16x32_bf16(w1, hf[g][1], acc, 0, 0, 0);
#pragma unroll
      for (int r = 0; r < 4; ++r)
#pragma unroll
        for (int c = 0; c < 3; ++c)
          macc1[g][r][c] = fmaf(v1h[g][c], acc[r], macc1[g][r][c]);
    }
  }

  // ---- finish msg1 (reduce i-partition across lq groups), scale, write msg rows ----
#pragma unroll
  for (int g = 0; g < 4; ++g)
#pragma unroll
    for (int r = 0; r < 4; ++r)
#pragma unroll
      for (int c = 0; c < 3; ++c) {
        float x = macc1[g][r][c];
        x += __shfl_xor(x, 16);
        x += __shfl_xor(x, 32);
        macc1[g][r][c] = x * kInvSqrt20;
      }
#pragma unroll
  for (int g = 0; g < 4; ++g) {
    char* rp = ub + (wv * 64 + g * 16 + lc) * kRowB;
    *(f32x4*)(rp + lq * 16) =
        f32x4{macc0[g][0] * kInvSqrt20, macc0[g][1] * kInvSqrt20,
              macc0[g][2] * kInvSqrt20, macc0[g][3] * kInvSqrt20};
    f32x4 m1;
    if (lq == 1)
      m1 = f32x4{macc1[g][0][0], macc1[g][0][1], macc1[g][0][2], macc1[g][1][0]};
    else if (lq == 2)
      m1 = f32x4{macc1[g][1][1], macc1[g][1][2], macc1[g][2][0], macc1[g][2][1]};
    else
      m1 = f32x4{macc1[g][2][2], macc1[g][3][0], macc1[g][3][1], macc1[g][3][2]};
    if (lq != 0) *(f32x4*)(rp + 48 + lq * 16) = m1;
  }

  // ---- read back own msg, segmented wave reduction, one atomic per segment head ----
  float msg[28];
  {
    const char* rp = ub + tid * kRowB;
#pragma unroll
    for (int c = 0; c < 7; ++c) {
      const f32x4 v = *(const f32x4*)(rp + c * 16);
      msg[c * 4 + 0] = v[0];
      msg[c * 4 + 1] = v[1];
      msg[c * 4 + 2] = v[2];
      msg[c * 4 + 3] = v[3];
    }
  }
#pragma unroll
  for (int d = 1; d < 64; d <<= 1) {
    const int od = __shfl_down(dstv, d);
    const bool same = (lane + d < 64) && (od == dstv);
#pragma unroll
    for (int j = 0; j < 28; j++) {
      const float ov = __shfl_down(msg[j], d);
      if (same) msg[j] += ov;
    }
  }
  const int pd = __shfl_up(dstv, 1);
  if ((lane == 0 || pd != dstv) && dstv >= 0) {
    float* ap = agg + (size_t)dstv * kAttr;
#pragma unroll
    for (int j = 0; j < 28; j++) atomicAdd(ap + j, msg[j]);
  }
}

__global__ __launch_bounds__(256) void tfn_finalize_kernel(
    const float* __restrict__ node_attr, const int* __restrict__ cnt,
    float* __restrict__ out, int total) {
  const int i = blockIdx.x * blockDim.x + threadIdx.x;
  if (i >= total) return;
  const int n = i / kAttr;
  const float c = fmaxf((float)cnt[n], 1.0f);
  out[i] = node_attr[i] + out[i] / c;
}

extern "C" void kernel_launch(void* const* d_in, const int* in_sizes, int n_in,
                              void* d_out, int out_size, void* d_ws, size_t ws_size,
                              hipStream_t stream) {
  const float* node_attr = (const float*)d_in[0];
  const float* pos = (const float*)d_in[1];
  const float* W1 = (const float*)d_in[2];
  const float* b1 = (const float*)d_in[3];
  const float* W2 = (const float*)d_in[4];
  const float* b2 = (const float*)d_in[5];
  const int* edge_index = (const int*)d_in[6];

  const int N = in_sizes[0] / kAttr;
  const int E = in_sizes[6] / 2;

  // ws layout: [img1 12288B][img2 51200B][cnt N][cur N][ssrc E][sdst E]
  char* wsc = (char*)d_ws;
  unsigned short* img1 = (unsigned short*)wsc;
  unsigned short* img2 = (unsigned short*)(wsc + kImg1Bytes);
  int* cnt = (int*)(wsc + kImg1Bytes + kImg2Bytes);
  int* cur = cnt + N;
  int* ssrc = cur + N;
  int* sdst = ssrc + E;
  const size_t need_full =
      (size_t)kImg1Bytes + kImg2Bytes + (size_t)(2 * N + 2 * E) * sizeof(int);
  const bool sorted = (ws_size >= need_full);

  float* agg = (float*)d_out;

  hipMemsetAsync(d_out, 0, (size_t)out_size * sizeof(float), stream);
  hipMemsetAsync(cnt, 0, (size_t)N * sizeof(int), stream);

  prep_kernel<<<(96 * 64 + 64 * 400 + 255) / 256, 256, 0, stream>>>(W1, W2, img1, img2);

  const int eblocks = (E + 255) / 256;
  hist_kernel<<<eblocks, 256, 0, stream>>>(edge_index, cnt, E);

  const int* usrc;
  const int* udst;
  if (sorted) {
    scan_kernel<<<1, 256, 0, stream>>>(cnt, cur, N);
    scatter_kernel<<<eblocks, 256, 0, stream>>>(edge_index, cur, ssrc, sdst, E);
    usrc = ssrc;
    udst = sdst;
  } else {
    usrc = edge_index;       // unsorted fallback: correct, just more atomics
    udst = edge_index + E;
  }

  tfn_mfma_kernel<<<eblocks, 256, 0, stream>>>(
      node_attr, pos, b1, b2, (const char*)img1, (const char*)img2, usrc, udst, agg, E);

  const int total = N * kAttr;
  tfn_finalize_kernel<<<(total + 255) / 256, 256, 0, stream>>>(
      node_attr, cnt, (float*)d_out, total);
}